// Round 1
// baseline (657.005 us; speedup 1.0000x reference)
//
#include <hip/hip_runtime.h>
#include <math.h>

#define P_DIM 1024
#define R_DIM 128
#define M_DIM 128

// ---------------------------------------------------------------------------
// Phase 1: scores[p] = nei[p]>0 ? dot(rela[p,:], att_w)+att_b : -1e-6
// ~50% of pairs have nei==0 -> their 512 B rela rows are NEVER loaded.
// v2: wave owns 64 consecutive pairs; 4 pairs concurrent (16 lanes/pair,
// 2 float4 each = 512 B/pair contiguous), 4-level butterfly (was 5), and the
// per-iteration nei shfl replaced by one __ballot -> bit tests (0 DS ops).
// DS ops/wave: 192 -> 64. Coalesced 256 B nei prefetch + 256 B score store.
// ---------------------------------------------------------------------------
__global__ __launch_bounds__(256) void scores_kernel(
    const float* __restrict__ rela,
    const int*   __restrict__ nei,
    const float* __restrict__ att_w,
    const float* __restrict__ att_b,
    float* __restrict__ scores)
{
    const int t    = threadIdx.x;
    const int wv   = t >> 6;            // wave within block (0..3)
    const int lane = t & 63;
    const int g    = lane >> 4;         // which of 4 concurrent pairs
    const int l16  = lane & 15;

    const float4* w4p = reinterpret_cast<const float4*>(att_w);
    const float4 wa   = w4p[l16];        // att_w[ l16*4      .. ]
    const float4 wb   = w4p[l16 + 16];   // att_w[(l16+16)*4  .. ]
    const float  bias = att_b[0];
    const float4* r4  = reinterpret_cast<const float4*>(rela);

    const int W     = blockIdx.x * 4 + wv;   // global wave id (16384 waves)
    const int pbase = W * 64;                // wave owns pairs [pbase, pbase+64)

    // coalesced nei prefetch: lane k holds nei for pair pbase+k,
    // then one ballot gives the whole wave's mask in a 64-bit reg.
    const int n_all = nei[pbase + lane];
    const unsigned long long bm = __ballot(n_all > 0);

    float my_score = -1e-6f;                 // lane k's output for pair pbase+k

    // group g processes pairs pbase + 16*g + it  (owner lane = 16*g + it)
    #pragma unroll 4
    for (int it = 0; it < 16; ++it) {
        const int k    = g * 16 + it;        // pair slot within wave
        const int pair = pbase + k;
        const bool on  = (bm >> k) & 1ull;   // per-16-lane-group uniform
        float s = 0.f;
        if (on) {                            // exec-masked: skips 512 B chunk
            const size_t base = (size_t)pair * 32;
            const float4 v1 = r4[base + l16];
            const float4 v2 = r4[base + 16 + l16];
            s = v1.x * wa.x + v1.y * wa.y + v1.z * wa.z + v1.w * wa.w
              + v2.x * wb.x + v2.y * wb.y + v2.z * wb.z + v2.w * wb.w;
        }
        s += __shfl_xor(s, 8);               // xor<16 stays within the group
        s += __shfl_xor(s, 4);
        s += __shfl_xor(s, 2);
        s += __shfl_xor(s, 1);
        // all 16 lanes of group g hold the pair's sum; park in owner lane
        if (l16 == it && on) my_score = s + bias;
    }

    scores[pbase + lane] = my_score;         // coalesced 256 B store
}

// ---------------------------------------------------------------------------
// Phase 2: masked softmax over j (exact ref semantics: non-neighbors become
// -1e-6 and DO contribute to the denominator; weights then zeroed), followed
// by out[i,:] = weights[i,:] @ hidden.
// v2: 512 threads/block (8 waves/CU, was 4) -> 2x latency hiding, half the
// serial jq chain per thread. Waves 0-3 do the 4 row softmaxes; all 8 waves
// do the matmul with 64-j chunks. LDS 16+32 = 48 KB.
// ---------------------------------------------------------------------------
__device__ __forceinline__ float fcomp(const float4& v, int k) {
    return k == 0 ? v.x : k == 1 ? v.y : k == 2 ? v.z : v.w;
}

__global__ __launch_bounds__(512) void attn_kernel(
    const float* __restrict__ scores,
    const int* __restrict__ nei,
    const float* __restrict__ hidden,
    float* __restrict__ out)
{
    __shared__ float  wsm[4][P_DIM];       // softmax weights, 16 KB
    __shared__ float4 part[4][16][32];     // matmul partials, 32 KB

    const int t    = threadIdx.x;
    const int wid  = t >> 6;               // wave id (0..7)
    const int lane = t & 63;
    const int i0   = blockIdx.x << 2;

    // ---- waves 0-3: per-wave softmax of row i0+wid (16 elements/lane) ----
    if (wid < 4) {
        const int i = i0 + wid;
        const float4* s4p = reinterpret_cast<const float4*>(scores + (size_t)i * P_DIM);
        const int4*   n4p = reinterpret_cast<const int4*>(nei + (size_t)i * P_DIM);

        float pv[16];
        unsigned mbits = 0;
        float lmax = -3.0e38f;
        #pragma unroll
        for (int c = 0; c < 4; ++c) {
            const int idx = c * 64 + lane;     // float4 index within row
            const float4 s4 = s4p[idx];
            const int4   n4 = n4p[idx];
            const float v0 = (n4.x > 0) ? s4.x : -1e-6f;
            const float v1 = (n4.y > 0) ? s4.y : -1e-6f;
            const float v2 = (n4.z > 0) ? s4.z : -1e-6f;
            const float v3 = (n4.w > 0) ? s4.w : -1e-6f;
            mbits |= ((n4.x > 0) ? 1u : 0u) << (c * 4 + 0);
            mbits |= ((n4.y > 0) ? 1u : 0u) << (c * 4 + 1);
            mbits |= ((n4.z > 0) ? 1u : 0u) << (c * 4 + 2);
            mbits |= ((n4.w > 0) ? 1u : 0u) << (c * 4 + 3);
            pv[c * 4 + 0] = v0; pv[c * 4 + 1] = v1;
            pv[c * 4 + 2] = v2; pv[c * 4 + 3] = v3;
            lmax = fmaxf(lmax, fmaxf(fmaxf(v0, v1), fmaxf(v2, v3)));
        }
        #pragma unroll
        for (int off = 32; off >= 1; off >>= 1)
            lmax = fmaxf(lmax, __shfl_xor(lmax, off));

        float lsum = 0.f;
        #pragma unroll
        for (int k = 0; k < 16; ++k) {
            const float e = __expf(pv[k] - lmax);
            pv[k] = e;
            lsum += e;
        }
        #pragma unroll
        for (int off = 32; off >= 1; off >>= 1)
            lsum += __shfl_xor(lsum, off);
        const float inv = 1.0f / lsum;

        #pragma unroll
        for (int c = 0; c < 4; ++c) {
            const int idx = c * 64 + lane;
            float4 o;
            o.x = ((mbits >> (c * 4 + 0)) & 1u) ? pv[c * 4 + 0] * inv : 0.f;
            o.y = ((mbits >> (c * 4 + 1)) & 1u) ? pv[c * 4 + 1] * inv : 0.f;
            o.z = ((mbits >> (c * 4 + 2)) & 1u) ? pv[c * 4 + 2] * inv : 0.f;
            o.w = ((mbits >> (c * 4 + 3)) & 1u) ? pv[c * 4 + 3] * inv : 0.f;
            reinterpret_cast<float4*>(wsm[wid])[idx] = o;
        }
    }
    __syncthreads();

    // ---- matmul: thread owns float4-column c4, j-group h (64 j's) ----
    const int c4 = t & 31;
    const int h  = t >> 5;                 // 0..15

    float4 acc[4];
    #pragma unroll
    for (int r = 0; r < 4; ++r) acc[r] = make_float4(0.f, 0.f, 0.f, 0.f);

    const int jbase = h * 64;
    #pragma unroll 2
    for (int jq = 0; jq < 16; ++jq) {
        const int j = jbase + jq * 4;
        float4 wq[4];
        #pragma unroll
        for (int r = 0; r < 4; ++r)
            wq[r] = *reinterpret_cast<const float4*>(&wsm[r][j]);  // LDS broadcast b128
        float4 hv[4];
        #pragma unroll
        for (int k = 0; k < 4; ++k)
            hv[k] = reinterpret_cast<const float4*>(hidden + (size_t)(j + k) * M_DIM)[c4];
        #pragma unroll
        for (int r = 0; r < 4; ++r) {
            #pragma unroll
            for (int k = 0; k < 4; ++k) {
                const float wc = fcomp(wq[r], k);
                acc[r].x += wc * hv[k].x;
                acc[r].y += wc * hv[k].y;
                acc[r].z += wc * hv[k].z;
                acc[r].w += wc * hv[k].w;
            }
        }
    }

    #pragma unroll
    for (int r = 0; r < 4; ++r) part[r][h][c4] = acc[r];
    __syncthreads();

    if (t < 128) {
        const int r = t >> 5;
        const int c = t & 31;
        float4 sum = part[r][0][c];
        #pragma unroll
        for (int hh = 1; hh < 16; ++hh) {
            const float4 p = part[r][hh][c];
            sum.x += p.x; sum.y += p.y; sum.z += p.z; sum.w += p.w;
        }
        reinterpret_cast<float4*>(out + (size_t)(i0 + r) * M_DIM)[c] = sum;
    }
}

// ---------------------------------------------------------------------------
extern "C" void kernel_launch(void* const* d_in, const int* in_sizes, int n_in,
                              void* d_out, int out_size, void* d_ws, size_t ws_size,
                              hipStream_t stream) {
    const float* hidden = (const float*)d_in[0];   // [1024,128]
    const float* rela   = (const float*)d_in[1];   // [1024,1024,128]
    // d_in[2] corr_index: unused by the reference
    const int*   nei    = (const int*)d_in[3];     // [1024,1024]
    const float* att_w  = (const float*)d_in[4];   // [128]
    const float* att_b  = (const float*)d_in[5];   // [1]
    float* out    = (float*)d_out;                 // [1024,128]
    float* scores = (float*)d_ws;                  // [1024*1024] fp32 = 4 MB scratch

    // 16384 waves, 64 pairs each = 1M pairs
    scores_kernel<<<4096, 256, 0, stream>>>(rela, nei, att_w, att_b, scores);
    attn_kernel<<<P_DIM / 4, 512, 0, stream>>>(scores, nei, hidden, out);
}